// Round 8
// baseline (58.550 us; speedup 1.0000x reference)
//
#include <hip/hip_runtime.h>
#include <math.h>

// CTransformer on MI355X, round 8: round 7's T3 dbuf pipeline with the Ct
// LDS-overflow fixed (epilogue scratch now exactly fits Bs[1] via XOR swizzle).
//   k_prep     : Wqkv/Wout fp32->bf16 + pad_k/pad_v vectors (LN(0)=ln_b)
//   k_ln_qkv   : fused LayerNorm + QKV GEMM, 32-pix blocks, dbuf W staging
//   k_attn_proj: fused attention + out-proj, 32-pix blocks, dbuf W staging

#define NPIX 16384
#define HW   4096
#define CDIM 256

typedef short  bf16x8 __attribute__((ext_vector_type(8)));
typedef float  f32x4  __attribute__((ext_vector_type(4)));
typedef unsigned short u16x8 __attribute__((ext_vector_type(8)));

__device__ inline float bf2f(unsigned short u) {
    unsigned v = ((unsigned)u) << 16;
    return __builtin_bit_cast(float, v);
}
__device__ inline unsigned short f2bf(float f) {   // round-to-nearest-even
    unsigned u = __builtin_bit_cast(unsigned, f);
    u += 0x7FFFu + ((u >> 16) & 1u);
    return (unsigned short)(u >> 16);
}

// ---- prep: weight conversions + pad vectors --------------------------------
__global__ __launch_bounds__(256) void k_prep(const float* __restrict__ Wqkv,
                                              const float* __restrict__ Wout,
                                              const float* __restrict__ bqkv,
                                              const float* __restrict__ lnb,
                                              unsigned short* __restrict__ Wqkvbf,
                                              unsigned short* __restrict__ Woutbf,
                                              float* __restrict__ pads) {
    int bid = blockIdx.x, t = threadIdx.x;
    if (bid < 768) {
        int i = bid * 256 + t;
        Wqkvbf[i] = f2bf(Wqkv[i]);
    } else if (bid < 1024) {
        int i = (bid - 768) * 256 + t;
        Woutbf[i] = f2bf(Wout[i]);
    } else {
        int d = (bid - 1024) * 256 + t;    // 0..511; k rows 256..511, v rows 512..767
        int row = 256 + d;
        const float* wrow = Wqkv + (size_t)row * CDIM;
        float s = bqkv[row];
        for (int c = 0; c < CDIM; ++c) s += lnb[c] * wrow[c];
        pads[d] = s;
    }
}

// Stage 256 rows x 32 k bf16 (16 KB) into linear LDS, source-side 4-slot
// swizzle: LDS slot s of row r holds source chunk (s ^ (r&3)).
__device__ inline void stageW32(const unsigned short* __restrict__ g,
                                unsigned short* lds, int t) {
    int lane = t & 63;
    int wv   = t >> 6;                     // 4 waves
    int rin  = lane >> 2;                  // 0..15 rows per call
    int slot = lane & 3;
    #pragma unroll
    for (int it = 0; it < 4; ++it) {
        int rbase = (wv * 4 + it) * 16;    // wave-uniform
        int row = rbase + rin;
        const unsigned short* src = g + (size_t)row * 256 + ((slot ^ (row & 3)) * 8);
        __builtin_amdgcn_global_load_lds(
            (const __attribute__((address_space(1))) void*)src,
            (__attribute__((address_space(3))) void*)(lds + rbase * 32),
            16, 0, 0);
    }
}

// ---- FUSED LayerNorm + QKV GEMM --------------------------------------------
// Block: 32 pixels x 768 d, 256 threads (4 waves). Grid 512, XCD-swizzled.
// As[32][256] bf16 8-slot-swizzled; Bs[2][256x32] double-buffered W chunks.
// LN scratch + epilogue Ct overlay the Bs[1] region (Ct fits EXACTLY: 8192 u16).
__global__ __launch_bounds__(256) void k_ln_qkv(const float* __restrict__ src,
                                                const float* __restrict__ lnw,
                                                const float* __restrict__ lnb,
                                                const unsigned short* __restrict__ Wbf,
                                                const float* __restrict__ bias,
                                                unsigned short* __restrict__ qkvbf) {
    __shared__ unsigned short As[32 * 256];     // 16 KB
    __shared__ unsigned short Bs[2][256 * 32];  // 2 x 16 KB

    int t = threadIdx.x;
    int bid = blockIdx.x;
    int sb = (bid & 7) * 64 + (bid >> 3);       // 512 = 8 XCDs x 64, bijective
    int n0 = sb * 32;
    int b = n0 >> 12, p0 = n0 & 4095;

    // prologue prefetch: chunk (pass0, k0=0) -> Bs[0]; hides under LN phase
    stageW32(Wbf, Bs[0], t);

    // ---- LN phase (scratch overlaid on Bs[1]) ------------------------------
    float* red  = (float*)(&Bs[1][0]);          // [8][33]
    float* red2 = red + 264;                    // [8][33]
    float* muv  = red + 528;                    // [32]
    float* rsv  = red + 560;                    // [32]
    int pix = t & 31, q = t >> 5;
    const float* sp = src + ((size_t)b * CDIM) * HW + p0 + pix;
    float x[32];
    float sum = 0.f, sq = 0.f;
    #pragma unroll
    for (int i = 0; i < 32; ++i) {
        x[i] = sp[(size_t)(q * 32 + i) * HW];
        sum += x[i]; sq += x[i] * x[i];
    }
    red[q * 33 + pix] = sum; red2[q * 33 + pix] = sq;
    __syncthreads();
    if (t < 32) {
        float s = 0.f, s2 = 0.f;
        #pragma unroll
        for (int qq = 0; qq < 8; ++qq) { s += red[qq * 33 + t]; s2 += red2[qq * 33 + t]; }
        float mu = s * (1.f / 256.f);
        float var = fmaxf(s2 * (1.f / 256.f) - mu * mu, 0.f);
        muv[t] = mu; rsv[t] = rsqrtf(var + 1e-5f);
    }
    __syncthreads();
    {
        float mu = muv[pix], rs = rsv[pix];
        #pragma unroll
        for (int c8 = 0; c8 < 4; ++c8) {
            u16x8 o8;
            #pragma unroll
            for (int j = 0; j < 8; ++j) {
                int c = q * 32 + c8 * 8 + j;
                float xn = (x[c8 * 8 + j] - mu) * rs * lnw[c] + lnb[c];
                o8[j] = f2bf(xn);
            }
            int chunk = q * 4 + c8;             // 0..31
            *(u16x8*)((char*)As + (pix * 512 + (((chunk & 7) ^ (pix & 7)) | (chunk & 24)) * 16)) = o8;
        }
    }
    __syncthreads();   // As visible; LN scratch dead -> Bs[1] free for staging

    // ---- GEMM phase: 3 d-passes x 8 k-chunks, stage(next) before compute ---
    int lane = t & 63, wv = t >> 6;
    int lr = lane & 15, lg = lane >> 4;

    for (int pass = 0; pass < 3; ++pass) {
        f32x4 acc[2][4] = {};
        #pragma unroll
        for (int kc = 0; kc < 8; ++kc) {
            int s = pass * 8 + kc;
            if (s < 23) {
                int ns = s + 1;
                stageW32(Wbf + (size_t)((ns >> 3) * 256) * 256 + (ns & 7) * 32,
                         Bs[ns & 1], t);
            }
            const unsigned short* B = Bs[s & 1];
            int chA = kc * 4 + lg;              // As k-chunk 0..31
            bf16x8 a[2], bb[4];
            #pragma unroll
            for (int i = 0; i < 2; ++i) {
                int r = i * 16 + lr;
                int sl = ((chA & 7) ^ (r & 7)) | (chA & 24);
                a[i] = *(bf16x8*)((char*)As + (r * 512 + sl * 16));
            }
            #pragma unroll
            for (int j = 0; j < 4; ++j) {
                int rb = wv * 64 + j * 16 + lr;
                bb[j] = *(bf16x8*)((char*)B + (rb * 64 + ((lg ^ (rb & 3)) * 16)));
            }
            #pragma unroll
            for (int i = 0; i < 2; ++i)
                #pragma unroll
                for (int j = 0; j < 4; ++j)
                    acc[i][j] = __builtin_amdgcn_mfma_f32_16x16x32_bf16(
                        a[i], bb[j], acc[i][j], 0, 0, 0);
            __syncthreads();                    // drains stage(next); buf swap safe
        }
        // ---- epilogue: Ct = Bs[1], [32][256] u16, 16B-chunk XOR swizzle ----
        // slot sl of row holds chunk ((sl&7)^(row&7)) | (sl&24)  -> fits 8192 u16
        int d0 = pass * 256;
        unsigned short* Ct = (unsigned short*)Bs[1];
        #pragma unroll
        for (int j = 0; j < 4; ++j) {
            float bj = bias[d0 + wv * 64 + j * 16 + lr];
            #pragma unroll
            for (int i = 0; i < 2; ++i)
                #pragma unroll
                for (int r2 = 0; r2 < 4; ++r2) {
                    int row = i * 16 + lg * 4 + r2;
                    int col = wv * 64 + j * 16 + lr;
                    int chunk = col >> 3;
                    int sl = ((chunk & 7) ^ (row & 7)) | (chunk & 24);
                    Ct[row * 256 + sl * 8 + (col & 7)] = f2bf(acc[i][j][r2] + bj);
                }
        }
        __syncthreads();
        int row = t >> 3, cb = t & 7;
        #pragma unroll
        for (int s2 = 0; s2 < 4; ++s2) {
            int chunk = cb + 8 * s2;            // 0..31
            int sl = ((chunk & 7) ^ (row & 7)) | (chunk & 24);
            bf16x8 v = *(bf16x8*)(Ct + row * 256 + sl * 8);
            *(bf16x8*)(qkvbf + (size_t)(n0 + row) * 768 + d0 + chunk * 8) = v;
        }
        __syncthreads();                        // Ct reads done before next stage
    }
}

// ---- FUSED attention + out-proj --------------------------------------------
// Block = 32 pixels x 256 out channels; 256 threads (4 waves). Grid 512,
// XCD-swizzled. Wout staged in 32-k double-buffered chunks (T3 2-phase);
// prologue stage hides under the attention phase.
__global__ __launch_bounds__(256) void k_attn_proj(const unsigned short* __restrict__ qkvbf,
                                                   const float* __restrict__ pads,
                                                   const unsigned short* __restrict__ Wbf,
                                                   const float* __restrict__ bias,
                                                   const float* __restrict__ src,
                                                   float* __restrict__ out) {
    __shared__ unsigned short Bt[32 * 264];     // attention out [pix][c] (16.9 KB)
    __shared__ unsigned short As2[2][256 * 32]; // W chunks, dbuf (2 x 16 KB)
    int t  = threadIdx.x;
    int bid = blockIdx.x;
    int sb  = (bid & 7) * 64 + (bid >> 3);      // 512 = 8 XCDs x 64, bijective
    int n0 = sb * 32;
    int b  = n0 >> 12;
    int p0 = n0 & 4095;

    // prologue prefetch: k-chunk 0 -> As2[0]; hides under attention phase
    stageW32(Wbf, As2[0], t);

    // ---- phase 1: attention, thread = (pixel, head) ----
    {
        int pix = t >> 3, h = t & 7;
        int n = n0 + pix;
        int p = n & 4095, hh0 = p >> 6, ww0 = p & 63;
        const float scale = 0.1767766952966369f;  // 1/sqrt(32)

        float qv[32];
        const unsigned short* qp = qkvbf + (size_t)n * 768 + h * 32;
        #pragma unroll
        for (int c8 = 0; c8 < 4; ++c8) {
            bf16x8 v = *(const bf16x8*)(qp + c8 * 8);
            #pragma unroll
            for (int j = 0; j < 8; ++j) qv[c8 * 8 + j] = bf2f((unsigned short)v[j]) * scale;
        }
        float sc[9];
        #pragma unroll
        for (int t9 = 0; t9 < 9; ++t9) {
            int dy = t9 / 3 - 1, dx = t9 % 3 - 1;
            int hh = hh0 + dy, ww = ww0 + dx;
            bool ok = ((unsigned)hh < 64u) && ((unsigned)ww < 64u);
            float a = 0.f;
            if (ok) {
                const unsigned short* kp = qkvbf + (size_t)(n + dy * 64 + dx) * 768 + 256 + h * 32;
                #pragma unroll
                for (int c8 = 0; c8 < 4; ++c8) {
                    bf16x8 v = *(const bf16x8*)(kp + c8 * 8);
                    #pragma unroll
                    for (int j = 0; j < 8; ++j) a += qv[c8 * 8 + j] * bf2f((unsigned short)v[j]);
                }
            } else {
                const float* pk = pads + h * 32;
                #pragma unroll
                for (int j = 0; j < 32; ++j) a += qv[j] * pk[j];
            }
            sc[t9] = a;
        }
        float m = sc[0];
        #pragma unroll
        for (int t9 = 1; t9 < 9; ++t9) m = fmaxf(m, sc[t9]);
        float s = 0.f;
        #pragma unroll
        for (int t9 = 0; t9 < 9; ++t9) { sc[t9] = __expf(sc[t9] - m); s += sc[t9]; }
        float inv = 1.0f / s;

        float ov[32];
        #pragma unroll
        for (int j = 0; j < 32; ++j) ov[j] = 0.f;
        #pragma unroll
        for (int t9 = 0; t9 < 9; ++t9) {
            int dy = t9 / 3 - 1, dx = t9 % 3 - 1;
            int hh = hh0 + dy, ww = ww0 + dx;
            bool ok = ((unsigned)hh < 64u) && ((unsigned)ww < 64u);
            float w = sc[t9] * inv;
            if (ok) {
                const unsigned short* vp = qkvbf + (size_t)(n + dy * 64 + dx) * 768 + 512 + h * 32;
                #pragma unroll
                for (int c8 = 0; c8 < 4; ++c8) {
                    bf16x8 v = *(const bf16x8*)(vp + c8 * 8);
                    #pragma unroll
                    for (int j = 0; j < 8; ++j) ov[c8 * 8 + j] += w * bf2f((unsigned short)v[j]);
                }
            } else {
                const float* pv = pads + 256 + h * 32;
                #pragma unroll
                for (int j = 0; j < 32; ++j) ov[j] += w * pv[j];
            }
        }
        #pragma unroll
        for (int c8 = 0; c8 < 4; ++c8) {
            u16x8 o8;
            #pragma unroll
            for (int j = 0; j < 8; ++j) o8[j] = f2bf(ov[c8 * 8 + j]);
            *(u16x8*)(Bt + pix * 264 + h * 32 + c8 * 8) = o8;
        }
    }
    __syncthreads();   // Bt visible; stage(0) drained

    // ---- phase 2: GEMM 256ch x 32pix x 256k, 8 dbuf k-chunks ----
    int lane = t & 63, wv = t >> 6;
    int lr = lane & 15, lg = lane >> 4;
    f32x4 acc[4][2] = {};
    #pragma unroll
    for (int kc = 0; kc < 8; ++kc) {
        if (kc < 7) stageW32(Wbf + (kc + 1) * 32, As2[(kc + 1) & 1], t);
        const unsigned short* A = As2[kc & 1];
        bf16x8 a[4], bb[2];
        #pragma unroll
        for (int i = 0; i < 4; ++i) {
            int r = wv * 64 + i * 16 + lr;
            a[i] = *(bf16x8*)((char*)A + (r * 64 + ((lg ^ (r & 3)) * 16)));
        }
        #pragma unroll
        for (int j = 0; j < 2; ++j)
            bb[j] = *(bf16x8*)(Bt + (j * 16 + lr) * 264 + kc * 32 + lg * 8);
        #pragma unroll
        for (int i = 0; i < 4; ++i)
            #pragma unroll
            for (int j = 0; j < 2; ++j)
                acc[i][j] = __builtin_amdgcn_mfma_f32_16x16x32_bf16(
                    a[i], bb[j], acc[i][j], 0, 0, 0);
        __syncthreads();
    }
    #pragma unroll
    for (int i = 0; i < 4; ++i) {
        #pragma unroll
        for (int r2 = 0; r2 < 4; ++r2) {
            int dg = wv * 64 + i * 16 + lg * 4 + r2;
            float bd = bias[dg];
            #pragma unroll
            for (int j = 0; j < 2; ++j) {
                int ng = p0 + j * 16 + lr;
                size_t idx = ((size_t)(b * CDIM + dg)) * HW + ng;
                out[idx] = acc[i][j][r2] + bd + src[idx];
            }
        }
    }
}

extern "C" void kernel_launch(void* const* d_in, const int* in_sizes, int n_in,
                              void* d_out, int out_size, void* d_ws, size_t ws_size,
                              hipStream_t stream) {
    const float* src  = (const float*)d_in[0];
    const float* lnw  = (const float*)d_in[1];
    const float* lnb  = (const float*)d_in[2];
    const float* Wqkv = (const float*)d_in[3];
    const float* bqkv = (const float*)d_in[4];
    const float* Wout = (const float*)d_in[5];
    const float* bout = (const float*)d_in[6];
    float* out = (float*)d_out;

    unsigned short* qkvbf  = (unsigned short*)d_ws;               // 16384*768
    unsigned short* Wqkvbf = qkvbf + (size_t)NPIX * 768;          // 768*256
    unsigned short* Woutbf = Wqkvbf + 768 * 256;                  // 256*256
    float* pads = (float*)(Woutbf + 256 * 256);                   // 512 floats

    k_prep<<<1026, 256, 0, stream>>>(Wqkv, Wout, bqkv, lnb, Wqkvbf, Woutbf, pads);
    k_ln_qkv<<<512, 256, 0, stream>>>(src, lnw, lnb, Wqkvbf, bqkv, qkvbf);
    k_attn_proj<<<512, 256, 0, stream>>>(qkvbf, pads, Woutbf, bout, src, out);
}